// Round 11
// baseline (652.808 us; speedup 1.0000x reference)
//
#include <hip/hip_runtime.h>
#include <hip/hip_fp16.h>
#include <math.h>

// Reference: bev (1024,1,120,120) fp32 -> out (1024,120) fp32.
// R15 green @600us: 4 imgs/block, uint2 texels, VALUBusy 76%, conflicts
// 1.344e8 (avg 2.1x DS slowdown), occupancy 44.8% (1 blk/CU).
// R16 shear REFUTED (+33% conflicts). R17 lane-remap REFUTED (+21%).
// Correct model: 8B texels force EVEN word strides -> wave uses <=16 of 32
// banks; case analysis predicts avg ~2.1x = measured. The texel SIZE, not
// the angle set, is the conflict source.
// R18 = R15 chassis + SoA PLANE SPLIT: Hab[y][x]=(A,B), Hcd[y][x]=(C,D),
// 4B __half2 texels. Word stride == texel stride (odd half the time) ->
// {w,w+1} pairs tile all 32 banks except stride=0 mod 4 (mild 2-4 way).
// Reads: 4x ds_read2_b32 (offsets 0/1, 123/124 per plane) = same 32B/lane,
// same 16 base cyc/sample. +1 VALU (2nd plane base). Identical half2 values
// and op sequence -> BIT-IDENTICAL output (canary 4.882812e-4).
#define NPIX  120
#define NS    120
#define NK    61             // independent bins 0..60; 61..119 mirrored
#define HSTR  123            // H cols: x = 0..122 (pads at 0, 121, 122)
#define HROWS 123            // H rows: y = 0..122 (pads at 0, 121, 122)
#define CHUNK 8              // angles in flight
#define NCHUNK 15            // 120 / 8
#define NT    960            // 8 angle-slots x 120, 15 waves

#if __has_builtin(__builtin_amdgcn_fractf)
#define FRACTF(x) __builtin_amdgcn_fractf(x)
#else
#define FRACTF(x) ((x) - floorf(x))
#endif

// LDS: Hab 60,516 + Hcd 60,516 + schunk dbl 30,720 + outAcc 976 + invN 16
//    = 152,744 B -> 1 block/CU, 15 waves.

__global__ void ring_fused(const float* __restrict__ bev,
                           float* __restrict__ out,
                           int B) {
    __shared__ __half2 Hab[HROWS * HSTR];    // (A,B) plane, 4B texels
    __shared__ __half2 Hcd[HROWS * HSTR];    // (C,D) plane, 4B texels
    __shared__ float4 schunk[2][CHUNK * NS]; // double-buffered sinogram rows
    __shared__ float4 outAcc[NK];
    __shared__ float  invN[4];               // per-image 1/norm (scalar stores)

    const int tid = threadIdx.x;          // 0..959
    const int b0  = blockIdx.x * 4;       // first image of the quad
    const int al  = tid / NS;             // angle slot 0..7
    const int sk  = tid - al * NS;        // s (radon) / k (Goertzel, if <61)
    if (b0 >= B) return;

    // ---- stage: build planes from 4 images (each word owned by 1 thread) ---
    const float* s0 = bev + (size_t)b0 * (NPIX * NPIX);
    const float* s1 = (b0 + 1 < B) ? bev + (size_t)(b0 + 1) * (NPIX * NPIX) : s0;
    const float* s2 = (b0 + 2 < B) ? bev + (size_t)(b0 + 2) * (NPIX * NPIX) : s0;
    const float* s3 = (b0 + 3 < B) ? bev + (size_t)(b0 + 3) * (NPIX * NPIX) : s0;
    for (int i = tid; i < HROWS * HSTR; i += NT) {
        int y = i / HSTR, x = i - y * HSTR;
        float va = 0.f, vb = 0.f, vc = 0.f, vd = 0.f;
        int gx = x - 1, gy = y - 1;
        if (gx >= 0 && gx < NPIX && gy >= 0 && gy < NPIX) {
            int o = gy * NPIX + gx;
            va = s0[o]; vb = s1[o]; vc = s2[o]; vd = s3[o];
        }
        Hab[i] = __floats2half2_rn(va, vb);
        Hcd[i] = __floats2half2_rn(vc, vd);
    }
    __syncthreads();

    // ---- per-thread Goertzel constant (k = sk, used where sk < 61) ---------
    const float coef = 2.f * cosf((float)sk * 0.052359877559829887f);  // 2cos(pi k/60)
    const float sgn  = (sk & 1) ? -1.f : 1.f;
    const double STEP = 6.283185307179586 / 119.0;   // linspace(0,2pi,120) step
    float acc0 = 0.f, acc1 = 0.f, acc2 = 0.f, acc3 = 0.f;

    for (int ch = 0; ch < NCHUNK; ++ch) {
        float4* buf = schunk[ch & 1];
        // ---- radon: sinogram[a = ch*8+al][s = sk] for FOUR images ----------
        {
            int a = ch * CHUNK + al;
            float theta = (float)((double)a * STEP);
            float st = sinf(theta), ct = cosf(theta);
            float sf  = (float)sk - 59.5f;
            float Ax  = fmaf(sf, ct, 60.5f);   // padded px at tv=0
            float Ay  = fmaf(sf, st, 60.5f);   // padded py at tv=0
            float nst = -st;
            float aA0 = 0.f, aA1 = 0.f, aB0 = 0.f, aB1 = 0.f;  // parity chains
            float aC0 = 0.f, aC1 = 0.f, aD0 = 0.f, aD1 = 0.f;
            float tv  = -59.5f;
            #pragma unroll 4
            for (int t = 0; t < NPIX; ++t) {
                float px = fmaf(tv, nst, Ax);
                float py = fmaf(tv, ct,  Ay);
                float cx = fminf(fmaxf(px, 0.f), 121.5f);  // v_med3
                float cy = fminf(fmaxf(py, 0.f), 121.5f);
                int   ix = (int)cx;                        // trunc = floor (cx>=0)
                int   iy = (int)cy;
                float wx = FRACTF(cx);                     // == cx - floor(cx)
                float wy = FRACTF(cy);
                int   w  = __mul24(iy, HSTR) + ix;
                __half2 ab00 = Hab[w];                     // ds_read2_b32 0/1
                __half2 ab01 = Hab[w + 1];
                __half2 ab10 = Hab[w + HSTR];              // ds_read2_b32 123/124
                __half2 ab11 = Hab[w + HSTR + 1];
                __half2 cd00 = Hcd[w];                     // ds_read2_b32 0/1
                __half2 cd01 = Hcd[w + 1];
                __half2 cd10 = Hcd[w + HSTR];              // ds_read2_b32 123/124
                __half2 cd11 = Hcd[w + HSTR + 1];
                __half2 wx2 = __float2half2_rn(wx);
                __half2 wy2 = __float2half2_rn(wy);
                __half2 abT = __hfma2(wx2, __hsub2(ab01, ab00), ab00);
                __half2 abB = __hfma2(wx2, __hsub2(ab11, ab10), ab10);
                __half2 abV = __hfma2(wy2, __hsub2(abB, abT), abT);
                __half2 cdT = __hfma2(wx2, __hsub2(cd01, cd00), cd00);
                __half2 cdB = __hfma2(wx2, __hsub2(cd11, cd10), cd10);
                __half2 cdV = __hfma2(wy2, __hsub2(cdB, cdT), cdT);
                if (t & 1) {
                    aA1 += __low2float(abV); aB1 += __high2float(abV);
                    aC1 += __low2float(cdV); aD1 += __high2float(cdV);
                } else {
                    aA0 += __low2float(abV); aB0 += __high2float(abV);
                    aC0 += __low2float(cdV); aD0 += __high2float(cdV);
                }
                tv += 1.f;
            }
            buf[al * NS + sk] = make_float4(aA0 + aA1, aB0 + aB1,
                                            aC0 + aC1, aD0 + aD1);
        }
        __syncthreads();

        // ---- Goertzel: |F[k = sk]| of row al, 4 images (sk < 61) -----------
        // (no trailing barrier: next chunk writes the OTHER schunk buffer;
        //  reuse of THIS buffer in chunk ch+2 is fenced by ch+1's barrier)
        if (sk < NK) {
            const float4* row = buf + al * NS;
            float u1a = 0.f, u2a = 0.f, u1b = 0.f, u2b = 0.f;
            float u1c = 0.f, u2c = 0.f, u1d = 0.f, u2d = 0.f;
            #pragma unroll 4
            for (int s = 0; s < 60; ++s) {
                float4 lo = row[s];            // broadcast ds_read_b128
                float4 hi = row[s + 60];
                float wa = fmaf(sgn, hi.x, lo.x);
                float wb = fmaf(sgn, hi.y, lo.y);
                float wc = fmaf(sgn, hi.z, lo.z);
                float wd = fmaf(sgn, hi.w, lo.w);
                float va = fmaf(coef, u1a, wa - u2a); u2a = u1a; u1a = va;
                float vb = fmaf(coef, u1b, wb - u2b); u2b = u1b; u1b = vb;
                float vc = fmaf(coef, u1c, wc - u2c); u2c = u1c; u1c = vc;
                float vd = fmaf(coef, u1d, wd - u2d); u2d = u1d; u1d = vd;
            }
            float pa = fmaf(u1a, u1a, fmaf(u2a, u2a, -coef * u1a * u2a));
            float pb = fmaf(u1b, u1b, fmaf(u2b, u2b, -coef * u1b * u2b));
            float pc = fmaf(u1c, u1c, fmaf(u2c, u2c, -coef * u1c * u2c));
            float pd = fmaf(u1d, u1d, fmaf(u2d, u2d, -coef * u1d * u2d));
            pa = fmaxf(pa, 0.f); pb = fmaxf(pb, 0.f);
            pc = fmaxf(pc, 0.f); pd = fmaxf(pd, 0.f);
            acc0 += sqrtf(fmaf(pa, (1.f / 120.f), 1e-15f));  // ortho + EPS_FFT
            acc1 += sqrtf(fmaf(pb, (1.f / 120.f), 1e-15f));
            acc2 += sqrtf(fmaf(pc, (1.f / 120.f), 1e-15f));
            acc3 += sqrtf(fmaf(pd, (1.f / 120.f), 1e-15f));
        }
    }
    __syncthreads();   // all Goertzel reads done before schunk[0] is reused

    // ---- reduce 8 angle-slot partials per bin (deterministic) --------------
    if (sk < NK) schunk[0][al * NS + sk] = make_float4(acc0, acc1, acc2, acc3);
    __syncthreads();
    if (tid < NK) {
        float sa = 0.f, sb = 0.f, sc = 0.f, sd = 0.f;
        for (int a2 = 0; a2 < CHUNK; ++a2) {
            float4 v = schunk[0][a2 * NS + tid];
            sa += v.x; sb += v.y; sc += v.z; sd += v.w;
        }
        outAcc[tid] = make_float4(sa, sb, sc, sd);
    }
    __syncthreads();

    // ---- L2 norm over the full mirrored 120-vector, one thread per image ---
    if (tid < 4) {
        float ssq = 0.f;
        for (int k = 0; k < NK; ++k) {
            float v = ((const float*)&outAcc[k])[tid];
            float wgt = (k == 0 || k == 60) ? 1.f : 2.f;
            ssq = fmaf(wgt * v, v, ssq);
        }
        invN[tid] = 1.f / fmaxf(sqrtf(ssq), 1e-12f);  // per-lane scalar store
    }
    __syncthreads();

    // ---- write fp32 output (Hermitian mirror), 4 images --------------------
    if (tid < 4 * NPIX) {
        int img = tid / NPIX;
        int j   = tid - img * NPIX;
        int k   = (j <= 60) ? j : (NPIX - j);
        int bb  = b0 + img;
        if (bb < B) {
            float v = ((const float*)&outAcc[k])[img] * invN[img];
            out[(size_t)bb * NPIX + j] = v;
        }
    }
}

extern "C" void kernel_launch(void* const* d_in, const int* in_sizes, int n_in,
                              void* d_out, int out_size, void* d_ws, size_t ws_size,
                              hipStream_t stream) {
    const float* bev = (const float*)d_in[0];
    float* out = (float*)d_out;
    int B = in_sizes[0] / (NPIX * NPIX);   // 1024
    int grid = (B + 3) / 4;                // 4 images per block
    hipLaunchKernelGGL(ring_fused, dim3(grid), dim3(NT), 0, stream, bev, out, B);
}

// Round 12
// 593.269 us; speedup vs baseline: 1.1004x; 1.1004x over previous
//
#include <hip/hip_runtime.h>
#include <hip/hip_fp16.h>
#include <math.h>

// Reference: bev (1024,1,120,120) fp32 -> out (1024,120) fp32.
// R15 green @600us: 4 imgs/block, uint2 8B texels, VALUBusy 76%, conflicts
// 1.344e8, occupancy 44.8% (1 blk/CU). R16 shear / R17 lane-remap / R18
// SoA-split all REFUTED: per-instr conflict cost is ~constant (4B: 5.9,
// 8B: 9.7 extra cyc/wave-instr) across ALL layouts -> scatter is stochastic
// (64 random addrs in 32 banks, max-load ~5, cost ~N/2.8 per m136). R15 is
// already optimal per image-sample in both DS instrs (0.5) and conflict cyc
// (4.85). Conflict engineering closed; LDS pipe floor ~400us/CU accepted.
// R19 = R15 + FP16 GROUP-ACCUMULATION (the last big VALU block):
//   inner loop accumulates abV/cdV in packed-fp16 chains (2x v_pk_add_f16
//   per sample, full-rate) and flushes to fp32 every 8 samples
//   (2 hadd2 + 4 cvt + 4 fadd per group). Accum cost 16 -> ~3.3 VALU/sample;
//   total ~44 -> ~31. NOT bit-identical: group sums <= 8 so fp16 ulp <= 2^-8,
//   rms ~0.02 abs on ~30 sinogram entries -> absmax expected ~1e-3-5e-3 vs
//   threshold 1.976e-2. If it fails, revert accumulation only.
#define NPIX  120
#define NS    120
#define NK    61             // independent bins 0..60; 61..119 mirrored
#define HSTR  123            // H cols: x = 0..122 (pads at 0, 121, 122)
#define HROWS 123            // H rows: y = 0..122 (pads at 0, 121, 122)
#define CHUNK 8              // angles in flight
#define NCHUNK 15            // 120 / 8
#define NT    960            // 8 angle-slots x 120, 15 waves

#if __has_builtin(__builtin_amdgcn_fractf)
#define FRACTF(x) __builtin_amdgcn_fractf(x)
#else
#define FRACTF(x) ((x) - floorf(x))
#endif

__device__ __forceinline__ __half2 lo_h2(uint2 q) { return *reinterpret_cast<__half2*>(&q.x); }
__device__ __forceinline__ __half2 hi_h2(uint2 q) { return *reinterpret_cast<__half2*>(&q.y); }

// LDS: H 123*123*8 (121,032) + schunk dbl 2*8*120*16 (30,720) + outAcc 976
//    + invN 16 = 152,744 B -> 1 block/CU, 15 waves.

__global__ void ring_fused(const float* __restrict__ bev,
                           float* __restrict__ out,
                           int B) {
    __shared__ uint2  H[HROWS * HSTR];       // (A,B,C,D) 4xfp16 padded image
    __shared__ float4 schunk[2][CHUNK * NS]; // double-buffered sinogram rows
    __shared__ float4 outAcc[NK];
    __shared__ float  invN[4];               // per-image 1/norm (scalar stores)

    const int tid = threadIdx.x;          // 0..959
    const int b0  = blockIdx.x * 4;       // first image of the quad
    const int al  = tid / NS;             // angle slot 0..7
    const int sk  = tid - al * NS;        // s (radon) / k (Goertzel, if <61)
    if (b0 >= B) return;

    // ---- stage: build H from 4 images (each 8B word owned by 1 thread) -----
    const float* s0 = bev + (size_t)b0 * (NPIX * NPIX);
    const float* s1 = (b0 + 1 < B) ? bev + (size_t)(b0 + 1) * (NPIX * NPIX) : s0;
    const float* s2 = (b0 + 2 < B) ? bev + (size_t)(b0 + 2) * (NPIX * NPIX) : s0;
    const float* s3 = (b0 + 3 < B) ? bev + (size_t)(b0 + 3) * (NPIX * NPIX) : s0;
    for (int i = tid; i < HROWS * HSTR; i += NT) {
        int y = i / HSTR, x = i - y * HSTR;
        float va = 0.f, vb = 0.f, vc = 0.f, vd = 0.f;
        int gx = x - 1, gy = y - 1;
        if (gx >= 0 && gx < NPIX && gy >= 0 && gy < NPIX) {
            int o = gy * NPIX + gx;
            va = s0[o]; vb = s1[o]; vc = s2[o]; vd = s3[o];
        }
        __half2 ab = __floats2half2_rn(va, vb);
        __half2 cd = __floats2half2_rn(vc, vd);
        H[i] = make_uint2(*reinterpret_cast<unsigned*>(&ab),
                          *reinterpret_cast<unsigned*>(&cd));
    }
    __syncthreads();

    // ---- per-thread Goertzel constant (k = sk, used where sk < 61) ---------
    const float coef = 2.f * cosf((float)sk * 0.052359877559829887f);  // 2cos(pi k/60)
    const float sgn  = (sk & 1) ? -1.f : 1.f;
    const double STEP = 6.283185307179586 / 119.0;   // linspace(0,2pi,120) step
    float acc0 = 0.f, acc1 = 0.f, acc2 = 0.f, acc3 = 0.f;

    for (int ch = 0; ch < NCHUNK; ++ch) {
        float4* buf = schunk[ch & 1];
        // ---- radon: sinogram[a = ch*8+al][s = sk] for FOUR images ----------
        {
            int a = ch * CHUNK + al;
            float theta = (float)((double)a * STEP);
            float st = sinf(theta), ct = cosf(theta);
            float sf  = (float)sk - 59.5f;
            float Ax  = fmaf(sf, ct, 60.5f);   // padded px at tv=0
            float Ay  = fmaf(sf, st, 60.5f);   // padded py at tv=0
            float nst = -st;
            const __half2 z2 = __float2half2_rn(0.f);
            float aA = 0.f, aB = 0.f, aC = 0.f, aD = 0.f;  // fp32 group sums
            float tv  = -59.5f;
            for (int tg = 0; tg < 15; ++tg) {          // 15 groups x 8 samples
                __half2 sAB0 = z2, sAB1 = z2, sCD0 = z2, sCD1 = z2;
                #pragma unroll
                for (int u = 0; u < 8; ++u) {
                    float px = fmaf(tv, nst, Ax);
                    float py = fmaf(tv, ct,  Ay);
                    float cx = fminf(fmaxf(px, 0.f), 121.5f);  // v_med3
                    float cy = fminf(fmaxf(py, 0.f), 121.5f);
                    int   ix = (int)cx;                        // trunc = floor
                    int   iy = (int)cy;
                    float wx = FRACTF(cx);                     // cx - floor(cx)
                    float wy = FRACTF(cy);
                    int   ai = __mul24(iy, HSTR) + ix;
                    uint2 q00 = H[ai];                         // ds_read2_b64 0/1
                    uint2 q01 = H[ai + 1];
                    uint2 q10 = H[ai + HSTR];                  // ds_read2_b64 123/124
                    uint2 q11 = H[ai + HSTR + 1];
                    __half2 wx2 = __float2half2_rn(wx);
                    __half2 wy2 = __float2half2_rn(wy);
                    __half2 abT = __hfma2(wx2, __hsub2(lo_h2(q01), lo_h2(q00)), lo_h2(q00));
                    __half2 abB = __hfma2(wx2, __hsub2(lo_h2(q11), lo_h2(q10)), lo_h2(q10));
                    __half2 abV = __hfma2(wy2, __hsub2(abB, abT), abT);
                    __half2 cdT = __hfma2(wx2, __hsub2(hi_h2(q01), hi_h2(q00)), hi_h2(q00));
                    __half2 cdB = __hfma2(wx2, __hsub2(hi_h2(q11), hi_h2(q10)), hi_h2(q10));
                    __half2 cdV = __hfma2(wy2, __hsub2(cdB, cdT), cdT);
                    if (u & 1) { sAB1 = __hadd2(sAB1, abV); sCD1 = __hadd2(sCD1, cdV); }
                    else       { sAB0 = __hadd2(sAB0, abV); sCD0 = __hadd2(sCD0, cdV); }
                    tv += 1.f;
                }
                __half2 sAB = __hadd2(sAB0, sAB1);   // group sum <= 8 in fp16
                __half2 sCD = __hadd2(sCD0, sCD1);
                aA += __low2float(sAB);  aB += __high2float(sAB);
                aC += __low2float(sCD);  aD += __high2float(sCD);
            }
            buf[al * NS + sk] = make_float4(aA, aB, aC, aD);
        }
        __syncthreads();

        // ---- Goertzel: |F[k = sk]| of row al, 4 images (sk < 61) -----------
        // (no trailing barrier: next chunk writes the OTHER schunk buffer;
        //  reuse of THIS buffer in chunk ch+2 is fenced by ch+1's barrier)
        if (sk < NK) {
            const float4* row = buf + al * NS;
            float u1a = 0.f, u2a = 0.f, u1b = 0.f, u2b = 0.f;
            float u1c = 0.f, u2c = 0.f, u1d = 0.f, u2d = 0.f;
            #pragma unroll 4
            for (int s = 0; s < 60; ++s) {
                float4 lo = row[s];            // broadcast ds_read_b128
                float4 hi = row[s + 60];
                float wa = fmaf(sgn, hi.x, lo.x);
                float wb = fmaf(sgn, hi.y, lo.y);
                float wc = fmaf(sgn, hi.z, lo.z);
                float wd = fmaf(sgn, hi.w, lo.w);
                float va = fmaf(coef, u1a, wa - u2a); u2a = u1a; u1a = va;
                float vb = fmaf(coef, u1b, wb - u2b); u2b = u1b; u1b = vb;
                float vc = fmaf(coef, u1c, wc - u2c); u2c = u1c; u1c = vc;
                float vd = fmaf(coef, u1d, wd - u2d); u2d = u1d; u1d = vd;
            }
            float pa = fmaf(u1a, u1a, fmaf(u2a, u2a, -coef * u1a * u2a));
            float pb = fmaf(u1b, u1b, fmaf(u2b, u2b, -coef * u1b * u2b));
            float pc = fmaf(u1c, u1c, fmaf(u2c, u2c, -coef * u1c * u2c));
            float pd = fmaf(u1d, u1d, fmaf(u2d, u2d, -coef * u1d * u2d));
            pa = fmaxf(pa, 0.f); pb = fmaxf(pb, 0.f);
            pc = fmaxf(pc, 0.f); pd = fmaxf(pd, 0.f);
            acc0 += sqrtf(fmaf(pa, (1.f / 120.f), 1e-15f));  // ortho + EPS_FFT
            acc1 += sqrtf(fmaf(pb, (1.f / 120.f), 1e-15f));
            acc2 += sqrtf(fmaf(pc, (1.f / 120.f), 1e-15f));
            acc3 += sqrtf(fmaf(pd, (1.f / 120.f), 1e-15f));
        }
    }
    __syncthreads();   // all Goertzel reads done before schunk[0] is reused

    // ---- reduce 8 angle-slot partials per bin (deterministic) --------------
    if (sk < NK) schunk[0][al * NS + sk] = make_float4(acc0, acc1, acc2, acc3);
    __syncthreads();
    if (tid < NK) {
        float sa = 0.f, sb = 0.f, sc = 0.f, sd = 0.f;
        for (int a2 = 0; a2 < CHUNK; ++a2) {
            float4 v = schunk[0][a2 * NS + tid];
            sa += v.x; sb += v.y; sc += v.z; sd += v.w;
        }
        outAcc[tid] = make_float4(sa, sb, sc, sd);
    }
    __syncthreads();

    // ---- L2 norm over the full mirrored 120-vector, one thread per image ---
    if (tid < 4) {
        float ssq = 0.f;
        for (int k = 0; k < NK; ++k) {
            float v = ((const float*)&outAcc[k])[tid];
            float wgt = (k == 0 || k == 60) ? 1.f : 2.f;
            ssq = fmaf(wgt * v, v, ssq);
        }
        invN[tid] = 1.f / fmaxf(sqrtf(ssq), 1e-12f);  // per-lane scalar store
    }
    __syncthreads();

    // ---- write fp32 output (Hermitian mirror), 4 images --------------------
    if (tid < 4 * NPIX) {
        int img = tid / NPIX;
        int j   = tid - img * NPIX;
        int k   = (j <= 60) ? j : (NPIX - j);
        int bb  = b0 + img;
        if (bb < B) {
            float v = ((const float*)&outAcc[k])[img] * invN[img];
            out[(size_t)bb * NPIX + j] = v;
        }
    }
}

extern "C" void kernel_launch(void* const* d_in, const int* in_sizes, int n_in,
                              void* d_out, int out_size, void* d_ws, size_t ws_size,
                              hipStream_t stream) {
    const float* bev = (const float*)d_in[0];
    float* out = (float*)d_out;
    int B = in_sizes[0] / (NPIX * NPIX);   // 1024
    int grid = (B + 3) / 4;                // 4 images per block
    hipLaunchKernelGGL(ring_fused, dim3(grid), dim3(NT), 0, stream, bev, out, B);
}

// Round 13
// 585.209 us; speedup vs baseline: 1.1155x; 1.0138x over previous
//
#include <hip/hip_runtime.h>
#include <hip/hip_fp16.h>
#include <math.h>

// Reference: bev (1024,1,120,120) fp32 -> out (1024,120) fp32.
// R19 green @593us: VALU 70% (413us), LDS pipe 67% (400us), conflicts 1.344e8
// (deterministic R15 value), occupancy 43.7% (1 blk/CU, 15 waves, max block
// 1024 caps waves). NEITHER pipe saturated: round=210 cyc/wave-sample vs
// VALU 147 + LDS 35 -> DEPENDENCY-LATENCY BOUND at 3.75 waves/SIMD.
// R20 = R19 + 1-AHEAD SOFTWARE PIPELINE in the radon loop: issue sample
// t+1's address math and its 2x ds_read2_b64 BEFORE consuming sample t's
// fp16 lerp chain -> ~120cyc LDS latency hides under ~147cyc independent
// work. Arithmetic unchanged (same values/order as R19 -> same absmax).
// Phantom prefetch at t=120 is clamp-safe (ai <= 15127 < 15129).
// Conflict-engineering history: R16 shear/R17 remap/R18 SoA all REFUTED;
// scatter is stochastic (64 balls/32 bins), R15 8B-texel layout is optimal.
#define NPIX  120
#define NS    120
#define NK    61             // independent bins 0..60; 61..119 mirrored
#define HSTR  123            // H cols: x = 0..122 (pads at 0, 121, 122)
#define HROWS 123            // H rows: y = 0..122 (pads at 0, 121, 122)
#define CHUNK 8              // angles in flight
#define NCHUNK 15            // 120 / 8
#define NT    960            // 8 angle-slots x 120, 15 waves

#if __has_builtin(__builtin_amdgcn_fractf)
#define FRACTF(x) __builtin_amdgcn_fractf(x)
#else
#define FRACTF(x) ((x) - floorf(x))
#endif

__device__ __forceinline__ __half2 lo_h2(uint2 q) { return *reinterpret_cast<__half2*>(&q.x); }
__device__ __forceinline__ __half2 hi_h2(uint2 q) { return *reinterpret_cast<__half2*>(&q.y); }

// LDS: H 123*123*8 (121,032) + schunk dbl 2*8*120*16 (30,720) + outAcc 976
//    + invN 16 = 152,744 B -> 1 block/CU, 15 waves.

__global__ void ring_fused(const float* __restrict__ bev,
                           float* __restrict__ out,
                           int B) {
    __shared__ uint2  H[HROWS * HSTR];       // (A,B,C,D) 4xfp16 padded image
    __shared__ float4 schunk[2][CHUNK * NS]; // double-buffered sinogram rows
    __shared__ float4 outAcc[NK];
    __shared__ float  invN[4];               // per-image 1/norm (scalar stores)

    const int tid = threadIdx.x;          // 0..959
    const int b0  = blockIdx.x * 4;       // first image of the quad
    const int al  = tid / NS;             // angle slot 0..7
    const int sk  = tid - al * NS;        // s (radon) / k (Goertzel, if <61)
    if (b0 >= B) return;

    // ---- stage: build H from 4 images (each 8B word owned by 1 thread) -----
    const float* s0 = bev + (size_t)b0 * (NPIX * NPIX);
    const float* s1 = (b0 + 1 < B) ? bev + (size_t)(b0 + 1) * (NPIX * NPIX) : s0;
    const float* s2 = (b0 + 2 < B) ? bev + (size_t)(b0 + 2) * (NPIX * NPIX) : s0;
    const float* s3 = (b0 + 3 < B) ? bev + (size_t)(b0 + 3) * (NPIX * NPIX) : s0;
    for (int i = tid; i < HROWS * HSTR; i += NT) {
        int y = i / HSTR, x = i - y * HSTR;
        float va = 0.f, vb = 0.f, vc = 0.f, vd = 0.f;
        int gx = x - 1, gy = y - 1;
        if (gx >= 0 && gx < NPIX && gy >= 0 && gy < NPIX) {
            int o = gy * NPIX + gx;
            va = s0[o]; vb = s1[o]; vc = s2[o]; vd = s3[o];
        }
        __half2 ab = __floats2half2_rn(va, vb);
        __half2 cd = __floats2half2_rn(vc, vd);
        H[i] = make_uint2(*reinterpret_cast<unsigned*>(&ab),
                          *reinterpret_cast<unsigned*>(&cd));
    }
    __syncthreads();

    // ---- per-thread Goertzel constant (k = sk, used where sk < 61) ---------
    const float coef = 2.f * cosf((float)sk * 0.052359877559829887f);  // 2cos(pi k/60)
    const float sgn  = (sk & 1) ? -1.f : 1.f;
    const double STEP = 6.283185307179586 / 119.0;   // linspace(0,2pi,120) step
    float acc0 = 0.f, acc1 = 0.f, acc2 = 0.f, acc3 = 0.f;

    for (int ch = 0; ch < NCHUNK; ++ch) {
        float4* buf = schunk[ch & 1];
        // ---- radon: sinogram[a = ch*8+al][s = sk] for FOUR images ----------
        {
            int a = ch * CHUNK + al;
            float theta = (float)((double)a * STEP);
            float st = sinf(theta), ct = cosf(theta);
            float sf  = (float)sk - 59.5f;
            float Ax  = fmaf(sf, ct, 60.5f);   // padded px at tv=0
            float Ay  = fmaf(sf, st, 60.5f);   // padded py at tv=0
            float nst = -st;
            const __half2 z2 = __float2half2_rn(0.f);
            float aA = 0.f, aB = 0.f, aC = 0.f, aD = 0.f;  // fp32 group sums

            // -- software pipeline: prologue loads sample t=0 ----------------
            float tv = -59.5f;
            float pxp = fmaf(tv, nst, Ax);
            float pyp = fmaf(tv, ct,  Ay);
            float cxp = fminf(fmaxf(pxp, 0.f), 121.5f);
            float cyp = fminf(fmaxf(pyp, 0.f), 121.5f);
            float wxc = FRACTF(cxp);
            float wyc = FRACTF(cyp);
            int   aic = __mul24((int)cyp, HSTR) + (int)cxp;
            uint2 q00 = H[aic];
            uint2 q01 = H[aic + 1];
            uint2 q10 = H[aic + HSTR];
            uint2 q11 = H[aic + HSTR + 1];

            for (int tg = 0; tg < 15; ++tg) {          // 15 groups x 8 samples
                __half2 sAB0 = z2, sAB1 = z2, sCD0 = z2, sCD1 = z2;
                #pragma unroll
                for (int u = 0; u < 8; ++u) {
                    // ---- prefetch sample t+1 (indep of current consume) ----
                    float tvn = tv + 1.f;
                    float px = fmaf(tvn, nst, Ax);
                    float py = fmaf(tvn, ct,  Ay);
                    float cx = fminf(fmaxf(px, 0.f), 121.5f);  // v_med3
                    float cy = fminf(fmaxf(py, 0.f), 121.5f);
                    float wxn = FRACTF(cx);
                    float wyn = FRACTF(cy);
                    int   ain = __mul24((int)cy, HSTR) + (int)cx;
                    uint2 n00 = H[ain];                        // ds_read2_b64
                    uint2 n01 = H[ain + 1];
                    uint2 n10 = H[ain + HSTR];                 // ds_read2_b64
                    uint2 n11 = H[ain + HSTR + 1];
                    // ---- consume current sample ----------------------------
                    __half2 wx2 = __float2half2_rn(wxc);
                    __half2 wy2 = __float2half2_rn(wyc);
                    __half2 abT = __hfma2(wx2, __hsub2(lo_h2(q01), lo_h2(q00)), lo_h2(q00));
                    __half2 abB = __hfma2(wx2, __hsub2(lo_h2(q11), lo_h2(q10)), lo_h2(q10));
                    __half2 abV = __hfma2(wy2, __hsub2(abB, abT), abT);
                    __half2 cdT = __hfma2(wx2, __hsub2(hi_h2(q01), hi_h2(q00)), hi_h2(q00));
                    __half2 cdB = __hfma2(wx2, __hsub2(hi_h2(q11), hi_h2(q10)), hi_h2(q10));
                    __half2 cdV = __hfma2(wy2, __hsub2(cdB, cdT), cdT);
                    if (u & 1) { sAB1 = __hadd2(sAB1, abV); sCD1 = __hadd2(sCD1, cdV); }
                    else       { sAB0 = __hadd2(sAB0, abV); sCD0 = __hadd2(sCD0, cdV); }
                    // ---- rotate pipeline -----------------------------------
                    q00 = n00; q01 = n01; q10 = n10; q11 = n11;
                    wxc = wxn; wyc = wyn; tv = tvn;
                }
                __half2 sAB = __hadd2(sAB0, sAB1);   // group sum <= 8 in fp16
                __half2 sCD = __hadd2(sCD0, sCD1);
                aA += __low2float(sAB);  aB += __high2float(sAB);
                aC += __low2float(sCD);  aD += __high2float(sCD);
            }
            buf[al * NS + sk] = make_float4(aA, aB, aC, aD);
        }
        __syncthreads();

        // ---- Goertzel: |F[k = sk]| of row al, 4 images (sk < 61) -----------
        // (no trailing barrier: next chunk writes the OTHER schunk buffer;
        //  reuse of THIS buffer in chunk ch+2 is fenced by ch+1's barrier)
        if (sk < NK) {
            const float4* row = buf + al * NS;
            float u1a = 0.f, u2a = 0.f, u1b = 0.f, u2b = 0.f;
            float u1c = 0.f, u2c = 0.f, u1d = 0.f, u2d = 0.f;
            #pragma unroll 4
            for (int s = 0; s < 60; ++s) {
                float4 lo = row[s];            // broadcast ds_read_b128
                float4 hi = row[s + 60];
                float wa = fmaf(sgn, hi.x, lo.x);
                float wb = fmaf(sgn, hi.y, lo.y);
                float wc = fmaf(sgn, hi.z, lo.z);
                float wd = fmaf(sgn, hi.w, lo.w);
                float va = fmaf(coef, u1a, wa - u2a); u2a = u1a; u1a = va;
                float vb = fmaf(coef, u1b, wb - u2b); u2b = u1b; u1b = vb;
                float vc = fmaf(coef, u1c, wc - u2c); u2c = u1c; u1c = vc;
                float vd = fmaf(coef, u1d, wd - u2d); u2d = u1d; u1d = vd;
            }
            float pa = fmaf(u1a, u1a, fmaf(u2a, u2a, -coef * u1a * u2a));
            float pb = fmaf(u1b, u1b, fmaf(u2b, u2b, -coef * u1b * u2b));
            float pc = fmaf(u1c, u1c, fmaf(u2c, u2c, -coef * u1c * u2c));
            float pd = fmaf(u1d, u1d, fmaf(u2d, u2d, -coef * u1d * u2d));
            pa = fmaxf(pa, 0.f); pb = fmaxf(pb, 0.f);
            pc = fmaxf(pc, 0.f); pd = fmaxf(pd, 0.f);
            acc0 += sqrtf(fmaf(pa, (1.f / 120.f), 1e-15f));  // ortho + EPS_FFT
            acc1 += sqrtf(fmaf(pb, (1.f / 120.f), 1e-15f));
            acc2 += sqrtf(fmaf(pc, (1.f / 120.f), 1e-15f));
            acc3 += sqrtf(fmaf(pd, (1.f / 120.f), 1e-15f));
        }
    }
    __syncthreads();   // all Goertzel reads done before schunk[0] is reused

    // ---- reduce 8 angle-slot partials per bin (deterministic) --------------
    if (sk < NK) schunk[0][al * NS + sk] = make_float4(acc0, acc1, acc2, acc3);
    __syncthreads();
    if (tid < NK) {
        float sa = 0.f, sb = 0.f, sc = 0.f, sd = 0.f;
        for (int a2 = 0; a2 < CHUNK; ++a2) {
            float4 v = schunk[0][a2 * NS + tid];
            sa += v.x; sb += v.y; sc += v.z; sd += v.w;
        }
        outAcc[tid] = make_float4(sa, sb, sc, sd);
    }
    __syncthreads();

    // ---- L2 norm over the full mirrored 120-vector, one thread per image ---
    if (tid < 4) {
        float ssq = 0.f;
        for (int k = 0; k < NK; ++k) {
            float v = ((const float*)&outAcc[k])[tid];
            float wgt = (k == 0 || k == 60) ? 1.f : 2.f;
            ssq = fmaf(wgt * v, v, ssq);
        }
        invN[tid] = 1.f / fmaxf(sqrtf(ssq), 1e-12f);  // per-lane scalar store
    }
    __syncthreads();

    // ---- write fp32 output (Hermitian mirror), 4 images --------------------
    if (tid < 4 * NPIX) {
        int img = tid / NPIX;
        int j   = tid - img * NPIX;
        int k   = (j <= 60) ? j : (NPIX - j);
        int bb  = b0 + img;
        if (bb < B) {
            float v = ((const float*)&outAcc[k])[img] * invN[img];
            out[(size_t)bb * NPIX + j] = v;
        }
    }
}

extern "C" void kernel_launch(void* const* d_in, const int* in_sizes, int n_in,
                              void* d_out, int out_size, void* d_ws, size_t ws_size,
                              hipStream_t stream) {
    const float* bev = (const float*)d_in[0];
    float* out = (float*)d_out;
    int B = in_sizes[0] / (NPIX * NPIX);   // 1024
    int grid = (B + 3) / 4;                // 4 images per block
    hipLaunchKernelGGL(ring_fused, dim3(grid), dim3(NT), 0, stream, bev, out, B);
}

// Round 14
// 582.772 us; speedup vs baseline: 1.1202x; 1.0042x over previous
//
#include <hip/hip_runtime.h>
#include <hip/hip_fp16.h>
#include <math.h>

// Reference: bev (1024,1,120,120) fp32 -> out (1024,120) fp32.
// R19 green @593us, R20 (1-ahead pipeline) NULL @585us, VALUBusy stuck 70%,
// VGPR 52 unchanged -> compiler already does 1-ahead. Steady state: VALU
// 0.99M cyc/CU, LDS 0.96M (432k base + 525k conflicts), wall 1.40M: both
// pipes ~70%, latency-bound at 3.75 waves/SIMD (LDS-capped; 2-img/block
// has more waves but more instrs = 691us measured R14).
// R21 = DEEP BATCHED PREFETCH: VGPR is NOT the constraint (52 of 128 used;
// LDS caps waves anyway). Per 4-sample batch: run 4 front-ends (~80cyc
// independent VALU), issue all 8 ds_read2_b64 into q[4][4] (32 VGPR, 8
// outstanding, lgkmcnt cap 15 ok), then consume 4. Load->use distance grows
// ~40 -> ~90-150cyc, hiding LDS latency + conflict variance under in-wave
// ILP. Same ops, same order as R19 (parity accumulate preserved) ->
// absmax exactly 4.882812e-4. VGPR est ~92; MUST stay <=128 (4 waves/SIMD
// needed for the 15-wave block).
// History: R16 shear / R17 remap / R18 SoA REFUTED (conflicts stochastic,
// R15 8B-texel layout optimal); R13 pk-f32 half-rate; R13 t-window wave-max.
#define NPIX  120
#define NS    120
#define NK    61             // independent bins 0..60; 61..119 mirrored
#define HSTR  123            // H cols: x = 0..122 (pads at 0, 121, 122)
#define HROWS 123            // H rows: y = 0..122 (pads at 0, 121, 122)
#define CHUNK 8              // angles in flight
#define NCHUNK 15            // 120 / 8
#define NT    960            // 8 angle-slots x 120, 15 waves

#if __has_builtin(__builtin_amdgcn_fractf)
#define FRACTF(x) __builtin_amdgcn_fractf(x)
#else
#define FRACTF(x) ((x) - floorf(x))
#endif

__device__ __forceinline__ __half2 lo_h2(uint2 q) { return *reinterpret_cast<__half2*>(&q.x); }
__device__ __forceinline__ __half2 hi_h2(uint2 q) { return *reinterpret_cast<__half2*>(&q.y); }

// LDS: H 123*123*8 (121,032) + schunk dbl 2*8*120*16 (30,720) + outAcc 976
//    + invN 16 = 152,744 B -> 1 block/CU, 15 waves.

__global__ void ring_fused(const float* __restrict__ bev,
                           float* __restrict__ out,
                           int B) {
    __shared__ uint2  H[HROWS * HSTR];       // (A,B,C,D) 4xfp16 padded image
    __shared__ float4 schunk[2][CHUNK * NS]; // double-buffered sinogram rows
    __shared__ float4 outAcc[NK];
    __shared__ float  invN[4];               // per-image 1/norm (scalar stores)

    const int tid = threadIdx.x;          // 0..959
    const int b0  = blockIdx.x * 4;       // first image of the quad
    const int al  = tid / NS;             // angle slot 0..7
    const int sk  = tid - al * NS;        // s (radon) / k (Goertzel, if <61)
    if (b0 >= B) return;

    // ---- stage: build H from 4 images (each 8B word owned by 1 thread) -----
    const float* s0 = bev + (size_t)b0 * (NPIX * NPIX);
    const float* s1 = (b0 + 1 < B) ? bev + (size_t)(b0 + 1) * (NPIX * NPIX) : s0;
    const float* s2 = (b0 + 2 < B) ? bev + (size_t)(b0 + 2) * (NPIX * NPIX) : s0;
    const float* s3 = (b0 + 3 < B) ? bev + (size_t)(b0 + 3) * (NPIX * NPIX) : s0;
    for (int i = tid; i < HROWS * HSTR; i += NT) {
        int y = i / HSTR, x = i - y * HSTR;
        float va = 0.f, vb = 0.f, vc = 0.f, vd = 0.f;
        int gx = x - 1, gy = y - 1;
        if (gx >= 0 && gx < NPIX && gy >= 0 && gy < NPIX) {
            int o = gy * NPIX + gx;
            va = s0[o]; vb = s1[o]; vc = s2[o]; vd = s3[o];
        }
        __half2 ab = __floats2half2_rn(va, vb);
        __half2 cd = __floats2half2_rn(vc, vd);
        H[i] = make_uint2(*reinterpret_cast<unsigned*>(&ab),
                          *reinterpret_cast<unsigned*>(&cd));
    }
    __syncthreads();

    // ---- per-thread Goertzel constant (k = sk, used where sk < 61) ---------
    const float coef = 2.f * cosf((float)sk * 0.052359877559829887f);  // 2cos(pi k/60)
    const float sgn  = (sk & 1) ? -1.f : 1.f;
    const double STEP = 6.283185307179586 / 119.0;   // linspace(0,2pi,120) step
    float acc0 = 0.f, acc1 = 0.f, acc2 = 0.f, acc3 = 0.f;

    for (int ch = 0; ch < NCHUNK; ++ch) {
        float4* buf = schunk[ch & 1];
        // ---- radon: sinogram[a = ch*8+al][s = sk] for FOUR images ----------
        {
            int a = ch * CHUNK + al;
            float theta = (float)((double)a * STEP);
            float st = sinf(theta), ct = cosf(theta);
            float sf  = (float)sk - 59.5f;
            float Ax  = fmaf(sf, ct, 60.5f);   // padded px at tv=0
            float Ay  = fmaf(sf, st, 60.5f);   // padded py at tv=0
            float nst = -st;
            const __half2 z2 = __float2half2_rn(0.f);
            float aA = 0.f, aB = 0.f, aC = 0.f, aD = 0.f;  // fp32 group sums
            float tv  = -59.5f;
            for (int tg = 0; tg < 15; ++tg) {          // 15 groups x 8 samples
                __half2 sAB0 = z2, sAB1 = z2, sCD0 = z2, sCD1 = z2;
                #pragma unroll
                for (int h = 0; h < 2; ++h) {          // 2 batches of 4
                    // -- batch front-end: 4 samples, issue all 8 DS reads ----
                    uint2 q[4][4];
                    float wxs[4], wys[4];
                    #pragma unroll
                    for (int u = 0; u < 4; ++u) {
                        float px = fmaf(tv, nst, Ax);
                        float py = fmaf(tv, ct,  Ay);
                        float cx = fminf(fmaxf(px, 0.f), 121.5f);  // v_med3
                        float cy = fminf(fmaxf(py, 0.f), 121.5f);
                        int   ix = (int)cx;                        // trunc=floor
                        int   iy = (int)cy;
                        wxs[u] = FRACTF(cx);                       // cx-floor(cx)
                        wys[u] = FRACTF(cy);
                        int   ai = __mul24(iy, HSTR) + ix;
                        q[u][0] = H[ai];                           // ds_read2_b64
                        q[u][1] = H[ai + 1];
                        q[u][2] = H[ai + HSTR];                    // ds_read2_b64
                        q[u][3] = H[ai + HSTR + 1];
                        tv += 1.f;
                    }
                    // -- batch consume: 4 samples (parity = u&1, as R19) -----
                    #pragma unroll
                    for (int u = 0; u < 4; ++u) {
                        __half2 wx2 = __float2half2_rn(wxs[u]);
                        __half2 wy2 = __float2half2_rn(wys[u]);
                        __half2 abT = __hfma2(wx2, __hsub2(lo_h2(q[u][1]), lo_h2(q[u][0])), lo_h2(q[u][0]));
                        __half2 abB = __hfma2(wx2, __hsub2(lo_h2(q[u][3]), lo_h2(q[u][2])), lo_h2(q[u][2]));
                        __half2 abV = __hfma2(wy2, __hsub2(abB, abT), abT);
                        __half2 cdT = __hfma2(wx2, __hsub2(hi_h2(q[u][1]), hi_h2(q[u][0])), hi_h2(q[u][0]));
                        __half2 cdB = __hfma2(wx2, __hsub2(hi_h2(q[u][3]), hi_h2(q[u][2])), hi_h2(q[u][2]));
                        __half2 cdV = __hfma2(wy2, __hsub2(cdB, cdT), cdT);
                        if (u & 1) { sAB1 = __hadd2(sAB1, abV); sCD1 = __hadd2(sCD1, cdV); }
                        else       { sAB0 = __hadd2(sAB0, abV); sCD0 = __hadd2(sCD0, cdV); }
                    }
                }
                __half2 sAB = __hadd2(sAB0, sAB1);   // group sum <= 8 in fp16
                __half2 sCD = __hadd2(sCD0, sCD1);
                aA += __low2float(sAB);  aB += __high2float(sAB);
                aC += __low2float(sCD);  aD += __high2float(sCD);
            }
            buf[al * NS + sk] = make_float4(aA, aB, aC, aD);
        }
        __syncthreads();

        // ---- Goertzel: |F[k = sk]| of row al, 4 images (sk < 61) -----------
        // (no trailing barrier: next chunk writes the OTHER schunk buffer;
        //  reuse of THIS buffer in chunk ch+2 is fenced by ch+1's barrier)
        if (sk < NK) {
            const float4* row = buf + al * NS;
            float u1a = 0.f, u2a = 0.f, u1b = 0.f, u2b = 0.f;
            float u1c = 0.f, u2c = 0.f, u1d = 0.f, u2d = 0.f;
            #pragma unroll 4
            for (int s = 0; s < 60; ++s) {
                float4 lo = row[s];            // broadcast ds_read_b128
                float4 hi = row[s + 60];
                float wa = fmaf(sgn, hi.x, lo.x);
                float wb = fmaf(sgn, hi.y, lo.y);
                float wc = fmaf(sgn, hi.z, lo.z);
                float wd = fmaf(sgn, hi.w, lo.w);
                float va = fmaf(coef, u1a, wa - u2a); u2a = u1a; u1a = va;
                float vb = fmaf(coef, u1b, wb - u2b); u2b = u1b; u1b = vb;
                float vc = fmaf(coef, u1c, wc - u2c); u2c = u1c; u1c = vc;
                float vd = fmaf(coef, u1d, wd - u2d); u2d = u1d; u1d = vd;
            }
            float pa = fmaf(u1a, u1a, fmaf(u2a, u2a, -coef * u1a * u2a));
            float pb = fmaf(u1b, u1b, fmaf(u2b, u2b, -coef * u1b * u2b));
            float pc = fmaf(u1c, u1c, fmaf(u2c, u2c, -coef * u1c * u2c));
            float pd = fmaf(u1d, u1d, fmaf(u2d, u2d, -coef * u1d * u2d));
            pa = fmaxf(pa, 0.f); pb = fmaxf(pb, 0.f);
            pc = fmaxf(pc, 0.f); pd = fmaxf(pd, 0.f);
            acc0 += sqrtf(fmaf(pa, (1.f / 120.f), 1e-15f));  // ortho + EPS_FFT
            acc1 += sqrtf(fmaf(pb, (1.f / 120.f), 1e-15f));
            acc2 += sqrtf(fmaf(pc, (1.f / 120.f), 1e-15f));
            acc3 += sqrtf(fmaf(pd, (1.f / 120.f), 1e-15f));
        }
    }
    __syncthreads();   // all Goertzel reads done before schunk[0] is reused

    // ---- reduce 8 angle-slot partials per bin (deterministic) --------------
    if (sk < NK) schunk[0][al * NS + sk] = make_float4(acc0, acc1, acc2, acc3);
    __syncthreads();
    if (tid < NK) {
        float sa = 0.f, sb = 0.f, sc = 0.f, sd = 0.f;
        for (int a2 = 0; a2 < CHUNK; ++a2) {
            float4 v = schunk[0][a2 * NS + tid];
            sa += v.x; sb += v.y; sc += v.z; sd += v.w;
        }
        outAcc[tid] = make_float4(sa, sb, sc, sd);
    }
    __syncthreads();

    // ---- L2 norm over the full mirrored 120-vector, one thread per image ---
    if (tid < 4) {
        float ssq = 0.f;
        for (int k = 0; k < NK; ++k) {
            float v = ((const float*)&outAcc[k])[tid];
            float wgt = (k == 0 || k == 60) ? 1.f : 2.f;
            ssq = fmaf(wgt * v, v, ssq);
        }
        invN[tid] = 1.f / fmaxf(sqrtf(ssq), 1e-12f);  // per-lane scalar store
    }
    __syncthreads();

    // ---- write fp32 output (Hermitian mirror), 4 images --------------------
    if (tid < 4 * NPIX) {
        int img = tid / NPIX;
        int j   = tid - img * NPIX;
        int k   = (j <= 60) ? j : (NPIX - j);
        int bb  = b0 + img;
        if (bb < B) {
            float v = ((const float*)&outAcc[k])[img] * invN[img];
            out[(size_t)bb * NPIX + j] = v;
        }
    }
}

extern "C" void kernel_launch(void* const* d_in, const int* in_sizes, int n_in,
                              void* d_out, int out_size, void* d_ws, size_t ws_size,
                              hipStream_t stream) {
    const float* bev = (const float*)d_in[0];
    float* out = (float*)d_out;
    int B = in_sizes[0] / (NPIX * NPIX);   // 1024
    int grid = (B + 3) / 4;                // 4 images per block
    hipLaunchKernelGGL(ring_fused, dim3(grid), dim3(NT), 0, stream, bev, out, B);
}

// Round 15
// 557.174 us; speedup vs baseline: 1.1716x; 1.0459x over previous
//
#include <hip/hip_runtime.h>
#include <hip/hip_fp16.h>
#include <math.h>

// Reference: bev (1024,1,120,120) fp32 -> out (1024,120) fp32.
// R19 @593, R20 1-ahead NULL @585, R21 batch-prefetch NULL @583 (VGPR stuck
// 52 -> compiler schedule already optimal; in-wave ILP exhausted). Both pipes
// ~70% (VALU 0.99M cyc/CU, LDS 0.96M incl 525k conflicts), wall 1.38M ->
// TLP-starved at 3.75 waves/SIMD, LDS-capped 1 blk/CU; 2-img/block = 1.62x
// VALU (modeled 667us, worse). Conflict engineering triple-refuted (R16-R18).
// R22 = two bit-identical ISSUE/TLP cuts:
//  (1) GOERTZEL COMPACTION: old mapping put active lanes in ALL 15 waves
//      (every wave issued the full 60x14 stream, ~34us/CU, <52% lanes).
//      New: alg=tid/61, kg=tid%61, active tid<488 -> 7.6 contiguous waves;
//      ~8 waves skip entirely and run ahead into next radon chunk (dbuf).
//  (2) NT 960->1024 (16 waves): radon al=tid>>7, sk=tid&127 (skip sk>=120);
//      +6.7% waves/SIMD for latency hiding.
// Thread roles permute; per-ray/per-bin math, order, slots unchanged ->
// absmax exactly 4.882812e-4. If gain <3%, structure is at its floor.
#define NPIX  120
#define NS    120
#define NK    61             // independent bins 0..60; 61..119 mirrored
#define HSTR  123            // H cols: x = 0..122 (pads at 0, 121, 122)
#define HROWS 123            // H rows: y = 0..122 (pads at 0, 121, 122)
#define CHUNK 8              // angles in flight
#define NCHUNK 15            // 120 / 8
#define NT    1024           // 16 waves
#define NGO   488            // 8 slots x 61 bins, compacted Goertzel threads

#if __has_builtin(__builtin_amdgcn_fractf)
#define FRACTF(x) __builtin_amdgcn_fractf(x)
#else
#define FRACTF(x) ((x) - floorf(x))
#endif

__device__ __forceinline__ __half2 lo_h2(uint2 q) { return *reinterpret_cast<__half2*>(&q.x); }
__device__ __forceinline__ __half2 hi_h2(uint2 q) { return *reinterpret_cast<__half2*>(&q.y); }

// LDS: H 123*123*8 (121,032) + schunk dbl 2*8*120*16 (30,720) + outAcc 976
//    + invN 16 = 152,744 B -> 1 block/CU, 16 waves.

__global__ void ring_fused(const float* __restrict__ bev,
                           float* __restrict__ out,
                           int B) {
    __shared__ uint2  H[HROWS * HSTR];       // (A,B,C,D) 4xfp16 padded image
    __shared__ float4 schunk[2][CHUNK * NS]; // double-buffered sinogram rows
    __shared__ float4 outAcc[NK];
    __shared__ float  invN[4];               // per-image 1/norm (scalar stores)

    const int tid = threadIdx.x;          // 0..1023
    const int b0  = blockIdx.x * 4;       // first image of the quad
    const int al  = tid >> 7;             // radon angle slot 0..7 (128 thr/slot)
    const int sk  = tid & 127;            // radon s index (active if <120)
    const int alg = tid / NK;             // Goertzel slot (compacted, tid<488)
    const int kg  = tid - alg * NK;       // Goertzel bin 0..60
    if (b0 >= B) return;

    // ---- stage: build H from 4 images (each 8B word owned by 1 thread) -----
    const float* s0 = bev + (size_t)b0 * (NPIX * NPIX);
    const float* s1 = (b0 + 1 < B) ? bev + (size_t)(b0 + 1) * (NPIX * NPIX) : s0;
    const float* s2 = (b0 + 2 < B) ? bev + (size_t)(b0 + 2) * (NPIX * NPIX) : s0;
    const float* s3 = (b0 + 3 < B) ? bev + (size_t)(b0 + 3) * (NPIX * NPIX) : s0;
    for (int i = tid; i < HROWS * HSTR; i += NT) {
        int y = i / HSTR, x = i - y * HSTR;
        float va = 0.f, vb = 0.f, vc = 0.f, vd = 0.f;
        int gx = x - 1, gy = y - 1;
        if (gx >= 0 && gx < NPIX && gy >= 0 && gy < NPIX) {
            int o = gy * NPIX + gx;
            va = s0[o]; vb = s1[o]; vc = s2[o]; vd = s3[o];
        }
        __half2 ab = __floats2half2_rn(va, vb);
        __half2 cd = __floats2half2_rn(vc, vd);
        H[i] = make_uint2(*reinterpret_cast<unsigned*>(&ab),
                          *reinterpret_cast<unsigned*>(&cd));
    }
    __syncthreads();

    // ---- per-thread Goertzel constant (bin kg, used where tid < 488) -------
    const float coef = 2.f * cosf((float)kg * 0.052359877559829887f);  // 2cos(pi k/60)
    const float sgn  = (kg & 1) ? -1.f : 1.f;
    const double STEP = 6.283185307179586 / 119.0;   // linspace(0,2pi,120) step
    float acc0 = 0.f, acc1 = 0.f, acc2 = 0.f, acc3 = 0.f;

    for (int ch = 0; ch < NCHUNK; ++ch) {
        float4* buf = schunk[ch & 1];
        // ---- radon: sinogram[a = ch*8+al][s = sk] for FOUR images ----------
        if (sk < NS) {
            int a = ch * CHUNK + al;
            float theta = (float)((double)a * STEP);
            float st = sinf(theta), ct = cosf(theta);
            float sf  = (float)sk - 59.5f;
            float Ax  = fmaf(sf, ct, 60.5f);   // padded px at tv=0
            float Ay  = fmaf(sf, st, 60.5f);   // padded py at tv=0
            float nst = -st;
            const __half2 z2 = __float2half2_rn(0.f);
            float aA = 0.f, aB = 0.f, aC = 0.f, aD = 0.f;  // fp32 group sums
            float tv  = -59.5f;
            for (int tg = 0; tg < 15; ++tg) {          // 15 groups x 8 samples
                __half2 sAB0 = z2, sAB1 = z2, sCD0 = z2, sCD1 = z2;
                #pragma unroll
                for (int u = 0; u < 8; ++u) {
                    float px = fmaf(tv, nst, Ax);
                    float py = fmaf(tv, ct,  Ay);
                    float cx = fminf(fmaxf(px, 0.f), 121.5f);  // v_med3
                    float cy = fminf(fmaxf(py, 0.f), 121.5f);
                    int   ix = (int)cx;                        // trunc = floor
                    int   iy = (int)cy;
                    float wx = FRACTF(cx);                     // cx - floor(cx)
                    float wy = FRACTF(cy);
                    int   ai = __mul24(iy, HSTR) + ix;
                    uint2 q00 = H[ai];                         // ds_read2_b64 0/1
                    uint2 q01 = H[ai + 1];
                    uint2 q10 = H[ai + HSTR];                  // ds_read2_b64 123/124
                    uint2 q11 = H[ai + HSTR + 1];
                    __half2 wx2 = __float2half2_rn(wx);
                    __half2 wy2 = __float2half2_rn(wy);
                    __half2 abT = __hfma2(wx2, __hsub2(lo_h2(q01), lo_h2(q00)), lo_h2(q00));
                    __half2 abB = __hfma2(wx2, __hsub2(lo_h2(q11), lo_h2(q10)), lo_h2(q10));
                    __half2 abV = __hfma2(wy2, __hsub2(abB, abT), abT);
                    __half2 cdT = __hfma2(wx2, __hsub2(hi_h2(q01), hi_h2(q00)), hi_h2(q00));
                    __half2 cdB = __hfma2(wx2, __hsub2(hi_h2(q11), hi_h2(q10)), hi_h2(q10));
                    __half2 cdV = __hfma2(wy2, __hsub2(cdB, cdT), cdT);
                    if (u & 1) { sAB1 = __hadd2(sAB1, abV); sCD1 = __hadd2(sCD1, cdV); }
                    else       { sAB0 = __hadd2(sAB0, abV); sCD0 = __hadd2(sCD0, cdV); }
                    tv += 1.f;
                }
                __half2 sAB = __hadd2(sAB0, sAB1);   // group sum <= 8 in fp16
                __half2 sCD = __hadd2(sCD0, sCD1);
                aA += __low2float(sAB);  aB += __high2float(sAB);
                aC += __low2float(sCD);  aD += __high2float(sCD);
            }
            buf[al * NS + sk] = make_float4(aA, aB, aC, aD);
        }
        __syncthreads();

        // ---- Goertzel: |F[kg]| of row alg, 4 images (compacted, tid<488) ---
        // (no trailing barrier: next chunk writes the OTHER schunk buffer;
        //  reuse of THIS buffer in chunk ch+2 is fenced by ch+1's barrier)
        if (tid < NGO) {
            const float4* row = buf + alg * NS;
            float u1a = 0.f, u2a = 0.f, u1b = 0.f, u2b = 0.f;
            float u1c = 0.f, u2c = 0.f, u1d = 0.f, u2d = 0.f;
            #pragma unroll 4
            for (int s = 0; s < 60; ++s) {
                float4 lo = row[s];            // near-broadcast ds_read_b128
                float4 hi = row[s + 60];
                float wa = fmaf(sgn, hi.x, lo.x);
                float wb = fmaf(sgn, hi.y, lo.y);
                float wc = fmaf(sgn, hi.z, lo.z);
                float wd = fmaf(sgn, hi.w, lo.w);
                float va = fmaf(coef, u1a, wa - u2a); u2a = u1a; u1a = va;
                float vb = fmaf(coef, u1b, wb - u2b); u2b = u1b; u1b = vb;
                float vc = fmaf(coef, u1c, wc - u2c); u2c = u1c; u1c = vc;
                float vd = fmaf(coef, u1d, wd - u2d); u2d = u1d; u1d = vd;
            }
            float pa = fmaf(u1a, u1a, fmaf(u2a, u2a, -coef * u1a * u2a));
            float pb = fmaf(u1b, u1b, fmaf(u2b, u2b, -coef * u1b * u2b));
            float pc = fmaf(u1c, u1c, fmaf(u2c, u2c, -coef * u1c * u2c));
            float pd = fmaf(u1d, u1d, fmaf(u2d, u2d, -coef * u1d * u2d));
            pa = fmaxf(pa, 0.f); pb = fmaxf(pb, 0.f);
            pc = fmaxf(pc, 0.f); pd = fmaxf(pd, 0.f);
            acc0 += sqrtf(fmaf(pa, (1.f / 120.f), 1e-15f));  // ortho + EPS_FFT
            acc1 += sqrtf(fmaf(pb, (1.f / 120.f), 1e-15f));
            acc2 += sqrtf(fmaf(pc, (1.f / 120.f), 1e-15f));
            acc3 += sqrtf(fmaf(pd, (1.f / 120.f), 1e-15f));
        }
    }
    __syncthreads();   // all Goertzel reads done before schunk[0] is reused

    // ---- reduce 8 slot partials per bin (deterministic) --------------------
    if (tid < NGO) schunk[0][alg * NS + kg] = make_float4(acc0, acc1, acc2, acc3);
    __syncthreads();
    if (tid < NK) {
        float sa = 0.f, sb = 0.f, sc = 0.f, sd = 0.f;
        for (int a2 = 0; a2 < CHUNK; ++a2) {
            float4 v = schunk[0][a2 * NS + tid];
            sa += v.x; sb += v.y; sc += v.z; sd += v.w;
        }
        outAcc[tid] = make_float4(sa, sb, sc, sd);
    }
    __syncthreads();

    // ---- L2 norm over the full mirrored 120-vector, one thread per image ---
    if (tid < 4) {
        float ssq = 0.f;
        for (int k = 0; k < NK; ++k) {
            float v = ((const float*)&outAcc[k])[tid];
            float wgt = (k == 0 || k == 60) ? 1.f : 2.f;
            ssq = fmaf(wgt * v, v, ssq);
        }
        invN[tid] = 1.f / fmaxf(sqrtf(ssq), 1e-12f);  // per-lane scalar store
    }
    __syncthreads();

    // ---- write fp32 output (Hermitian mirror), 4 images --------------------
    if (tid < 4 * NPIX) {
        int img = tid / NPIX;
        int j   = tid - img * NPIX;
        int k   = (j <= 60) ? j : (NPIX - j);
        int bb  = b0 + img;
        if (bb < B) {
            float v = ((const float*)&outAcc[k])[img] * invN[img];
            out[(size_t)bb * NPIX + j] = v;
        }
    }
}

extern "C" void kernel_launch(void* const* d_in, const int* in_sizes, int n_in,
                              void* d_out, int out_size, void* d_ws, size_t ws_size,
                              hipStream_t stream) {
    const float* bev = (const float*)d_in[0];
    float* out = (float*)d_out;
    int B = in_sizes[0] / (NPIX * NPIX);   // 1024
    int grid = (B + 3) / 4;                // 4 images per block
    hipLaunchKernelGGL(ring_fused, dim3(grid), dim3(NT), 0, stream, bev, out, B);
}